// Round 16
// baseline (159.894 us; speedup 1.0000x reference)
//
#include <hip/hip_runtime.h>
#include <hip/hip_fp16.h>

#define EMBED_DIM 64
#define NBMAX 1024          // max row buckets (scan assumes exactly 2*512)
#define RPB 128             // rows per bucket
#define RPB_SHIFT 7
#define CAP 6144            // slots/bucket: mean aligned fill ~5474, +8 sigma
#define CHUNK 8192          // edges per WG
#define SCAT_T 512
#define EPT (CHUNK / SCAT_T)
#define SENTINEL_KEY 0xFFFFFFFFu   // lr bits >= RPB -> skipped in bsort
// bscatter dynamic LDS: h + gbase + lbase (NBMAX ints each) + tsum[512] + rec[CHUNK]
#define SCAT_LDS (NBMAX * 4 * 3 + 512 * 4 + CHUNK * 8)

typedef float f32x8 __attribute__((ext_vector_type(8)));
typedef float f32x4 __attribute__((ext_vector_type(4)));

__device__ __forceinline__ int load_idx(const void* p, int e, bool i64) {
    return i64 ? (int)((const long long*)p)[e] : ((const int*)p)[e];
}

static inline size_t align_up(size_t v, size_t a) { return (v + a - 1) & ~(a - 1); }

// ---------------------------------------------------------------------------
// Detect index dtype (int64 values < 2^17 -> odd u32 words all zero) and zero
// per-bucket cursors. One WG, every call.
// ---------------------------------------------------------------------------
__global__ __launch_bounds__(1024) void detect_zero_kernel(
    const unsigned int* __restrict__ rows_u32, int* __restrict__ flag,
    int* __restrict__ gcur, int nb) {
    const int tid = threadIdx.x;
    if (tid == 0) {
        int nz = 0;
        for (int i = 1; i < 128; i += 2) nz += (rows_u32[i] != 0u);
        *flag = (nz == 0) ? 1 : 0;
    }
    if (tid < nb) gcur[tid] = 0;
}

// ---------------------------------------------------------------------------
// x (f32) -> xh (fp16, row-major N x 64).
// ---------------------------------------------------------------------------
__global__ __launch_bounds__(256) void xconv_kernel(
    const float* __restrict__ x, ushort* __restrict__ xh, int n8) {
    int i = blockIdx.x * 256 + threadIdx.x;
    if (i >= n8) return;
    float4 a = ((const float4*)x)[i * 2];
    float4 b = ((const float4*)x)[i * 2 + 1];
    ushort h[8];
    h[0] = __half_as_ushort(__float2half_rn(a.x));
    h[1] = __half_as_ushort(__float2half_rn(a.y));
    h[2] = __half_as_ushort(__float2half_rn(a.z));
    h[3] = __half_as_ushort(__float2half_rn(a.w));
    h[4] = __half_as_ushort(__float2half_rn(b.x));
    h[5] = __half_as_ushort(__float2half_rn(b.y));
    h[6] = __half_as_ushort(__float2half_rn(b.z));
    h[7] = __half_as_ushort(__float2half_rn(b.w));
    ((uint4*)xh)[i] = *(const uint4*)h;
}

// ---------------------------------------------------------------------------
// Phase 1 v2: LDS-STAGED binning. r15 wrote each (WG,bucket) run directly to
// global, leaving ~1200 partially-filled lines open per WG for the kernel's
// lifetime; with ~64 WGs/XCD that working set (>4MiB) thrashed L2 and each
// line was written ~2.5x (WRITE 85MB for 34MB payload, alignment didn't fix
// it). v2 scatters records into LDS (compact layout via 1024-bin scan), then
// copies each run out as complete 64B-aligned lines in one burst -- lines
// become fully dirty immediately, written back once.
// ---------------------------------------------------------------------------
__global__ __launch_bounds__(SCAT_T) void bscatter_kernel(
    const void* __restrict__ rows_p, const void* __restrict__ cols_p,
    const float* __restrict__ vals, int* __restrict__ gcur,
    uint2* __restrict__ recs, const int* __restrict__ flag_p,
    int n_edges, int nb) {
    extern __shared__ char smem[];
    int*   h     = (int*)smem;            // NBMAX counts / cursors
    int*   gbase = h + NBMAX;             // NBMAX global run bases
    int*   lbase = gbase + NBMAX;         // NBMAX LDS run bases (compact)
    int*   tsum  = lbase + NBMAX;         // 512 scan workspace
    uint2* rec   = (uint2*)(tsum + 512);  // CHUNK staged records

    const bool i64 = (*flag_p != 0);
    const int tid = threadIdx.x;
    const int c0e = blockIdx.x * CHUNK;
    int rloc[EPT];

    for (int i = tid; i < NBMAX; i += SCAT_T) h[i] = 0;
    __syncthreads();

    // pass 1: histogram (rows cached in registers)
    #pragma unroll
    for (int k = 0; k < EPT; ++k) {
        int e = c0e + k * SCAT_T + tid;
        int r = (e < n_edges) ? load_idx(rows_p, e, i64) : -1;
        rloc[k] = r;
        if (r >= 0) atomicAdd(&h[r >> RPB_SHIFT], 1);
    }
    __syncthreads();

    // scan 1024 counts (2 per thread) -> compact LDS bases; reserve aligned
    // global runs; zero cursors.
    const int b0 = 2 * tid, b1 = 2 * tid + 1;
    int cb0 = h[b0], cb1 = h[b1];
    int s = cb0 + cb1;
    tsum[tid] = s;
    __syncthreads();
    for (int d = 1; d < 512; d <<= 1) {
        int u = (tid >= d) ? tsum[tid - d] : 0;
        __syncthreads();
        tsum[tid] += u;
        __syncthreads();
    }
    {
        int run = tsum[tid] - s;
        lbase[b0] = run;
        lbase[b1] = run + cb0;
        int a0 = (cb0 + 7) & ~7, a1 = (cb1 + 7) & ~7;
        gbase[b0] = cb0 ? (b0 * CAP + atomicAdd(&gcur[b0], a0)) : 0;
        gbase[b1] = cb1 ? (b1 * CAP + atomicAdd(&gcur[b1], a1)) : 0;
        h[b0] = 0;
        h[b1] = 0;
    }
    __syncthreads();

    // pass 2: scatter records into LDS (cols/vals in 4-wide batches)
    #pragma unroll
    for (int k0 = 0; k0 < EPT; k0 += 4) {
        int cc[4]; float vv[4];
        #pragma unroll
        for (int j = 0; j < 4; ++j) {
            int e = c0e + (k0 + j) * SCAT_T + tid;
            if (rloc[k0 + j] >= 0) {
                cc[j] = load_idx(cols_p, e, i64);
                vv[j] = vals[e];
            }
        }
        #pragma unroll
        for (int j = 0; j < 4; ++j) {
            int r = rloc[k0 + j];
            if (r >= 0) {
                int b = r >> RPB_SHIFT;
                int pos = lbase[b] + atomicAdd(&h[b], 1);
                rec[pos] = make_uint2(
                    ((unsigned)(r & (RPB - 1)) << 20) | (unsigned)cc[j],
                    __float_as_uint(vv[j]));
            }
        }
    }
    __syncthreads();

    // copy-out: one wave per bucket, whole aligned run in one burst
    const int wave = tid >> 6, lane = tid & 63;
    for (int b = wave; b < nb; b += (SCAT_T / 64)) {
        int c = h[b];
        if (c == 0) continue;
        int ca = (c + 7) & ~7;
        int gb = gbase[b], lb = lbase[b];
        int lim = (b + 1) * CAP;
        for (int j = lane; j < ca; j += 64) {
            uint2 v = (j < c) ? rec[lb + j] : make_uint2(SENTINEL_KEY, 0u);
            int pos = gb + j;
            if (pos < lim) recs[pos] = v;   // overflow guard
        }
    }
}

// ---------------------------------------------------------------------------
// Phase 2: per-bucket counting sort (128 row bins), sentinel-skipping.
// recs2[pos] = {col, val_f32}, srange[row] = {start, end}.
// ---------------------------------------------------------------------------
__global__ __launch_bounds__(512) void bsort_kernel(
    const int* __restrict__ gcur, const uint2* __restrict__ recs,
    uint2* __restrict__ recs2, uint2* __restrict__ srange, int N) {
    __shared__ int cnt[RPB];
    __shared__ int scn[RPB];
    __shared__ int rbase[RPB];
    const int b = blockIdx.x;
    const int tid = threadIdx.x;
    const int s = b * CAP;
    int n = gcur[b];
    if (n > CAP) n = CAP;

    if (tid < RPB) cnt[tid] = 0;
    __syncthreads();

    for (int i = tid; i < n; i += 512) {
        unsigned lr = recs[s + i].x >> 20;
        if (lr < RPB) atomicAdd(&cnt[lr], 1);   // skip sentinels
    }
    __syncthreads();

    if (tid < RPB) scn[tid] = cnt[tid];
    __syncthreads();
    for (int d = 1; d < RPB; d <<= 1) {
        int u = (tid < RPB && tid >= d) ? scn[tid - d] : 0;
        __syncthreads();
        if (tid < RPB) scn[tid] += u;
        __syncthreads();
    }
    if (tid < RPB) {
        int excl = scn[tid] - cnt[tid];
        rbase[tid] = excl;
        int row = b * RPB + tid;
        if (row < N) srange[row] = make_uint2(s + excl, s + excl + cnt[tid]);
        cnt[tid] = 0;              // reuse as cursor
    }
    __syncthreads();

    for (int i = tid; i < n; i += 512) {
        uint2 e = recs[s + i];
        unsigned lr = e.x >> 20;
        if (lr < RPB) {
            int pos = s + rbase[lr] + atomicAdd(&cnt[lr], 1);
            recs2[pos] = make_uint2(e.x & 0xFFFFFu, e.y);
        }
    }
}

// ---------------------------------------------------------------------------
// Phase 3: single-pass row-parallel gather (r15 form: 8 lanes/row, fp16 x,
// f32 vals in records, cached loads, NT output stores).
// ---------------------------------------------------------------------------
__global__ __launch_bounds__(256) void gather_kernel(
    const uint2* __restrict__ srange, const uint2* __restrict__ recs2,
    const ushort* __restrict__ xh, float* __restrict__ out, int N) {
    int t = blockIdx.x * blockDim.x + threadIdx.x;
    int row = t >> 3;
    if (row >= N) return;
    const int lane = t & 7;

    uint2 rg = srange[row];
    int e = (int)rg.x;
    const int e_end = (int)rg.y;
    f32x8 A = {};

    #define ACC8(U, V)                                                     \
        {                                                                  \
            float2 f0 = __half22float2(*(const __half2*)&(U).x);           \
            float2 f1 = __half22float2(*(const __half2*)&(U).y);           \
            float2 f2 = __half22float2(*(const __half2*)&(U).z);           \
            float2 f3 = __half22float2(*(const __half2*)&(U).w);           \
            A[0] += (V) * f0.x; A[1] += (V) * f0.y;                        \
            A[2] += (V) * f1.x; A[3] += (V) * f1.y;                        \
            A[4] += (V) * f2.x; A[5] += (V) * f2.y;                        \
            A[6] += (V) * f3.x; A[7] += (V) * f3.y;                        \
        }

    for (; e + 4 <= e_end; e += 4) {
        uint2 r0 = recs2[e],     r1 = recs2[e + 1];
        uint2 r2 = recs2[e + 2], r3 = recs2[e + 3];
        uint4 a0 = ((const uint4*)(xh + (size_t)r0.x * EMBED_DIM))[lane];
        uint4 a1 = ((const uint4*)(xh + (size_t)r1.x * EMBED_DIM))[lane];
        uint4 a2 = ((const uint4*)(xh + (size_t)r2.x * EMBED_DIM))[lane];
        uint4 a3 = ((const uint4*)(xh + (size_t)r3.x * EMBED_DIM))[lane];
        float v0 = __uint_as_float(r0.y), v1 = __uint_as_float(r1.y);
        float v2 = __uint_as_float(r2.y), v3 = __uint_as_float(r3.y);
        ACC8(a0, v0); ACC8(a1, v1); ACC8(a2, v2); ACC8(a3, v3);
    }
    for (; e < e_end; ++e) {
        uint2 r0 = recs2[e];
        uint4 a0 = ((const uint4*)(xh + (size_t)r0.x * EMBED_DIM))[lane];
        ACC8(a0, __uint_as_float(r0.y));
    }
    #undef ACC8

    f32x4 o0 = {A[0], A[1], A[2], A[3]};
    f32x4 o1 = {A[4], A[5], A[6], A[7]};
    f32x4* op = (f32x4*)(out + (size_t)row * EMBED_DIM) + lane * 2;
    __builtin_nontemporal_store(o0, op);
    __builtin_nontemporal_store(o1, op + 1);
}

// ---------------------------------------------------------------------------
// Fallback: atomic COO (f32) if workspace/shape constraints violated.
// ---------------------------------------------------------------------------
__global__ __launch_bounds__(256) void spmv_coo_kernel(
    const void* __restrict__ rows_p, const void* __restrict__ cols_p,
    const float* __restrict__ vals, const float* __restrict__ x,
    float* __restrict__ out, const int* __restrict__ flag_p, int n_edges) {
    const bool i64 = (*flag_p != 0);
    const int lane16 = threadIdx.x & 15;
    long long t      = (long long)blockIdx.x * blockDim.x + threadIdx.x;
    long long stride = (long long)gridDim.x * blockDim.x;
    long long total  = (long long)n_edges * 16;
    for (; t < total; t += stride) {
        int e = (int)(t >> 4);
        int r = load_idx(rows_p, e, i64);
        int c = load_idx(cols_p, e, i64);
        float v = vals[e];
        float4 xv = ((const float4*)(x + (long long)c * EMBED_DIM))[lane16];
        float* o = out + (long long)r * EMBED_DIM + lane16 * 4;
        unsafeAtomicAdd(o + 0, xv.x * v);
        unsafeAtomicAdd(o + 1, xv.y * v);
        unsafeAtomicAdd(o + 2, xv.z * v);
        unsafeAtomicAdd(o + 3, xv.w * v);
    }
}

extern "C" void kernel_launch(void* const* d_in, const int* in_sizes, int n_in,
                              void* d_out, int out_size, void* d_ws, size_t ws_size,
                              hipStream_t stream) {
    const float* x    = (const float*)d_in[0];
    const void*  rows = d_in[1];
    const void*  cols = d_in[2];
    const float* vals = (const float*)d_in[3];
    float* out = (float*)d_out;
    const int E = in_sizes[1];
    const int N = out_size / EMBED_DIM;
    const int NB = (N + RPB - 1) >> RPB_SHIFT;

    // Workspace layout, every section 256B-aligned.
    char* ws = (char*)d_ws;
    size_t off = 0;
    int* flag = (int*)(ws + off);            off += 16;
    int* gcur = (int*)(ws + off);            off += (size_t)NBMAX * 4;
    off = align_up(off, 256);
    ushort* xh = (ushort*)(ws + off);        off += (size_t)N * EMBED_DIM * 2;
    off = align_up(off, 256);
    uint2* srange = (uint2*)(ws + off);      off += (size_t)N * 8;
    off = align_up(off, 256);
    uint2* recs = (uint2*)(ws + off);        off += (size_t)NB * CAP * 8;
    off = align_up(off, 256);
    uint2* recs2 = (uint2*)(ws + off);       off += (size_t)NB * CAP * 8;
    const size_t needed = off;

    if (ws_size < needed || NB > NBMAX || N > (1 << 20) ||
        (size_t)NB * CAP < (size_t)E / 2) {
        detect_zero_kernel<<<1, 1024, 0, stream>>>((const unsigned int*)rows,
                                                   flag, gcur, 0);
        (void)hipMemsetAsync(d_out, 0, (size_t)out_size * sizeof(float), stream);
        spmv_coo_kernel<<<8192, 256, 0, stream>>>(rows, cols, vals, x, out,
                                                  flag, E);
        return;
    }

    detect_zero_kernel<<<1, 1024, 0, stream>>>((const unsigned int*)rows,
                                               flag, gcur, NB);
    xconv_kernel<<<(N * 8 + 255) / 256, 256, 0, stream>>>(x, xh, N * 8);
    const int grid_c = (E + CHUNK - 1) / CHUNK;
    bscatter_kernel<<<grid_c, SCAT_T, SCAT_LDS, stream>>>(
        rows, cols, vals, gcur, recs, flag, E, NB);
    bsort_kernel<<<NB, 512, 0, stream>>>(gcur, recs, recs2, srange, N);
    const int grid_g = (N * 8 + 255) / 256;
    gather_kernel<<<grid_g, 256, 0, stream>>>(srange, recs2, xh, out, N);
}

// Round 17
// 151.031 us; speedup vs baseline: 1.0587x; 1.0587x over previous
//
#include <hip/hip_runtime.h>
#include <hip/hip_fp16.h>

#define EMBED_DIM 64
#define NBMAX 1024          // max row buckets (bscatter scan assumes 2*512)
#define RPB 128             // rows per bucket
#define RPB_SHIFT 7
#define CAP 6144            // slots/bucket: mean aligned fill ~5474, +8 sigma
#define CHUNK 8192          // edges per WG
#define SCAT_T 512
#define EPT (CHUNK / SCAT_T)
#define SENTINEL_KEY 0xFFFFFFFFu   // lr bits >= RPB -> skipped in bsort
// bscatter dynamic LDS: h/gbase/lbase (NBMAX ints each) + tsum[512] + rec[CHUNK]
#define SCAT_LDS (NBMAX * 4 * 3 + 512 * 4 + CHUNK * 8)
// bsort dynamic LDS: lrec[CAP] + cnt/scn/rbase (RPB ints each)
#define SORT_LDS (CAP * 8 + RPB * 4 * 3)

typedef float f32x8 __attribute__((ext_vector_type(8)));
typedef float f32x4 __attribute__((ext_vector_type(4)));

__device__ __forceinline__ int load_idx(const void* p, int e, bool i64) {
    return i64 ? (int)((const long long*)p)[e] : ((const int*)p)[e];
}

static inline size_t align_up(size_t v, size_t a) { return (v + a - 1) & ~(a - 1); }

// ---------------------------------------------------------------------------
// Fallback-path helper: detect index dtype + zero cursors (one WG).
// ---------------------------------------------------------------------------
__global__ __launch_bounds__(1024) void detect_zero_kernel(
    const unsigned int* __restrict__ rows_u32, int* __restrict__ flag,
    int* __restrict__ gcur, int nb) {
    const int tid = threadIdx.x;
    if (tid == 0) {
        int nz = 0;
        for (int i = 1; i < 128; i += 2) nz += (rows_u32[i] != 0u);
        *flag = (nz == 0) ? 1 : 0;
    }
    if (tid < nb) gcur[tid] = 0;
}

// ---------------------------------------------------------------------------
// x (f32) -> xh (fp16, row-major N x 64), with detect+cursor-zero fused into
// block 0 (saves a launch; flag/gcur are consumed by the LATER bscatter
// launch on the same stream, so ordering is guaranteed).
// ---------------------------------------------------------------------------
__global__ __launch_bounds__(256) void xconv_kernel(
    const float* __restrict__ x, ushort* __restrict__ xh, int n8,
    const unsigned int* __restrict__ rows_u32, int* __restrict__ flag,
    int* __restrict__ gcur, int nb) {
    if (blockIdx.x == 0) {
        if (threadIdx.x == 0) {
            int nz = 0;
            for (int i = 1; i < 128; i += 2) nz += (rows_u32[i] != 0u);
            *flag = (nz == 0) ? 1 : 0;
        }
        for (int j = threadIdx.x; j < nb; j += 256) gcur[j] = 0;
    }
    int i = blockIdx.x * 256 + threadIdx.x;
    if (i >= n8) return;
    float4 a = ((const float4*)x)[i * 2];
    float4 b = ((const float4*)x)[i * 2 + 1];
    ushort h[8];
    h[0] = __half_as_ushort(__float2half_rn(a.x));
    h[1] = __half_as_ushort(__float2half_rn(a.y));
    h[2] = __half_as_ushort(__float2half_rn(a.z));
    h[3] = __half_as_ushort(__float2half_rn(a.w));
    h[4] = __half_as_ushort(__float2half_rn(b.x));
    h[5] = __half_as_ushort(__float2half_rn(b.y));
    h[6] = __half_as_ushort(__float2half_rn(b.z));
    h[7] = __half_as_ushort(__float2half_rn(b.w));
    ((uint4*)xh)[i] = *(const uint4*)h;
}

// ---------------------------------------------------------------------------
// Phase 1: LDS-staged binning (r16, verified: WRITE 85->36MB). Histogram ->
// 1024-bin scan -> LDS scatter -> wave-per-bucket burst copy-out of complete
// 64B-aligned runs (sentinel-padded).
// ---------------------------------------------------------------------------
__global__ __launch_bounds__(SCAT_T) void bscatter_kernel(
    const void* __restrict__ rows_p, const void* __restrict__ cols_p,
    const float* __restrict__ vals, int* __restrict__ gcur,
    uint2* __restrict__ recs, const int* __restrict__ flag_p,
    int n_edges, int nb) {
    extern __shared__ char smem[];
    int*   h     = (int*)smem;            // NBMAX counts / cursors
    int*   gbase = h + NBMAX;             // NBMAX global run bases
    int*   lbase = gbase + NBMAX;         // NBMAX LDS run bases (compact)
    int*   tsum  = lbase + NBMAX;         // 512 scan workspace
    uint2* rec   = (uint2*)(tsum + 512);  // CHUNK staged records

    const bool i64 = (*flag_p != 0);
    const int tid = threadIdx.x;
    const int c0e = blockIdx.x * CHUNK;
    int rloc[EPT];

    for (int i = tid; i < NBMAX; i += SCAT_T) h[i] = 0;
    __syncthreads();

    #pragma unroll
    for (int k = 0; k < EPT; ++k) {
        int e = c0e + k * SCAT_T + tid;
        int r = (e < n_edges) ? load_idx(rows_p, e, i64) : -1;
        rloc[k] = r;
        if (r >= 0) atomicAdd(&h[r >> RPB_SHIFT], 1);
    }
    __syncthreads();

    const int b0 = 2 * tid, b1 = 2 * tid + 1;
    int cb0 = h[b0], cb1 = h[b1];
    int s = cb0 + cb1;
    tsum[tid] = s;
    __syncthreads();
    for (int d = 1; d < 512; d <<= 1) {
        int u = (tid >= d) ? tsum[tid - d] : 0;
        __syncthreads();
        tsum[tid] += u;
        __syncthreads();
    }
    {
        int run = tsum[tid] - s;
        lbase[b0] = run;
        lbase[b1] = run + cb0;
        int a0 = (cb0 + 7) & ~7, a1 = (cb1 + 7) & ~7;
        gbase[b0] = cb0 ? (b0 * CAP + atomicAdd(&gcur[b0], a0)) : 0;
        gbase[b1] = cb1 ? (b1 * CAP + atomicAdd(&gcur[b1], a1)) : 0;
        h[b0] = 0;
        h[b1] = 0;
    }
    __syncthreads();

    #pragma unroll
    for (int k0 = 0; k0 < EPT; k0 += 4) {
        int cc[4]; float vv[4];
        #pragma unroll
        for (int j = 0; j < 4; ++j) {
            int e = c0e + (k0 + j) * SCAT_T + tid;
            if (rloc[k0 + j] >= 0) {
                cc[j] = load_idx(cols_p, e, i64);
                vv[j] = vals[e];
            }
        }
        #pragma unroll
        for (int j = 0; j < 4; ++j) {
            int r = rloc[k0 + j];
            if (r >= 0) {
                int b = r >> RPB_SHIFT;
                int pos = lbase[b] + atomicAdd(&h[b], 1);
                rec[pos] = make_uint2(
                    ((unsigned)(r & (RPB - 1)) << 20) | (unsigned)cc[j],
                    __float_as_uint(vv[j]));
            }
        }
    }
    __syncthreads();

    const int wave = tid >> 6, lane = tid & 63;
    for (int b = wave; b < nb; b += (SCAT_T / 64)) {
        int c = h[b];
        if (c == 0) continue;
        int ca = (c + 7) & ~7;
        int gb = gbase[b], lb = lbase[b];
        int lim = (b + 1) * CAP;
        for (int j = lane; j < ca; j += 64) {
            uint2 v = (j < c) ? rec[lb + j] : make_uint2(SENTINEL_KEY, 0u);
            int pos = gb + j;
            if (pos < lim) recs[pos] = v;   // overflow guard
        }
    }
}

// ---------------------------------------------------------------------------
// Phase 2 v2: per-bucket counting sort with LDS-staged records -- the r16
// version read the 34MB record array from global TWICE (histogram pass +
// scatter pass); v2 stages into 48KB dynamic LDS on the first pass and the
// scatter pass reads LDS. recs2[pos]={col,val_f32}, srange[row]={start,end}.
// ---------------------------------------------------------------------------
__global__ __launch_bounds__(512) void bsort_kernel(
    const int* __restrict__ gcur, const uint2* __restrict__ recs,
    uint2* __restrict__ recs2, uint2* __restrict__ srange, int N) {
    extern __shared__ char smem[];
    uint2* lrec  = (uint2*)smem;          // CAP staged records
    int*   cnt   = (int*)(lrec + CAP);
    int*   scn   = cnt + RPB;
    int*   rbase = scn + RPB;
    const int b = blockIdx.x;
    const int tid = threadIdx.x;
    const int s = b * CAP;
    int n = gcur[b];
    if (n > CAP) n = CAP;

    if (tid < RPB) cnt[tid] = 0;
    __syncthreads();

    for (int i = tid; i < n; i += 512) {
        uint2 v = recs[s + i];
        lrec[i] = v;
        unsigned lr = v.x >> 20;
        if (lr < RPB) atomicAdd(&cnt[lr], 1);   // skip sentinels
    }
    __syncthreads();

    if (tid < RPB) scn[tid] = cnt[tid];
    __syncthreads();
    for (int d = 1; d < RPB; d <<= 1) {
        int u = (tid < RPB && tid >= d) ? scn[tid - d] : 0;
        __syncthreads();
        if (tid < RPB) scn[tid] += u;
        __syncthreads();
    }
    if (tid < RPB) {
        int excl = scn[tid] - cnt[tid];
        rbase[tid] = excl;
        int row = b * RPB + tid;
        if (row < N) srange[row] = make_uint2(s + excl, s + excl + cnt[tid]);
        cnt[tid] = 0;              // reuse as cursor
    }
    __syncthreads();

    for (int i = tid; i < n; i += 512) {
        uint2 e = lrec[i];
        unsigned lr = e.x >> 20;
        if (lr < RPB) {
            int pos = s + rbase[lr] + atomicAdd(&cnt[lr], 1);
            recs2[pos] = make_uint2(e.x & 0xFFFFFu, e.y);
        }
    }
}

// ---------------------------------------------------------------------------
// Phase 3 v2: row-parallel gather with PAIRED record loads. The r16 gather
// issued ~51M VMEM insts (1 xh + 1 recs2 load per edge per lane) -- issue
// bound at ~1/cyc/CU. v2 loads recs2 as uint4 (2 records, even-index 16B
// aligned; odd head peeled) -> 6 loads per 4 edges instead of 8.
// ---------------------------------------------------------------------------
__global__ __launch_bounds__(256) void gather_kernel(
    const uint2* __restrict__ srange, const uint2* __restrict__ recs2,
    const ushort* __restrict__ xh, float* __restrict__ out, int N) {
    int t = blockIdx.x * blockDim.x + threadIdx.x;
    int row = t >> 3;
    if (row >= N) return;
    const int lane = t & 7;

    uint2 rg = srange[row];
    int e = (int)rg.x;
    const int e_end = (int)rg.y;
    f32x8 A = {};

    #define ACC8(U, V)                                                     \
        {                                                                  \
            float2 f0 = __half22float2(*(const __half2*)&(U).x);           \
            float2 f1 = __half22float2(*(const __half2*)&(U).y);           \
            float2 f2 = __half22float2(*(const __half2*)&(U).z);           \
            float2 f3 = __half22float2(*(const __half2*)&(U).w);           \
            A[0] += (V) * f0.x; A[1] += (V) * f0.y;                        \
            A[2] += (V) * f1.x; A[3] += (V) * f1.y;                        \
            A[4] += (V) * f2.x; A[5] += (V) * f2.y;                        \
            A[6] += (V) * f3.x; A[7] += (V) * f3.y;                        \
        }
    #define ACC1(E)                                                        \
        {                                                                  \
            uint2 r0 = recs2[E];                                           \
            uint4 a0 = ((const uint4*)(xh + (size_t)r0.x * EMBED_DIM))[lane]; \
            ACC8(a0, __uint_as_float(r0.y));                               \
        }

    if (e < e_end && (e & 1)) { ACC1(e); ++e; }     // align to even index

    for (; e + 4 <= e_end; e += 4) {
        uint4 p0 = *(const uint4*)(recs2 + e);       // records e, e+1
        uint4 p1 = *(const uint4*)(recs2 + e + 2);   // records e+2, e+3
        uint4 a0 = ((const uint4*)(xh + (size_t)p0.x * EMBED_DIM))[lane];
        uint4 a1 = ((const uint4*)(xh + (size_t)p0.z * EMBED_DIM))[lane];
        uint4 a2 = ((const uint4*)(xh + (size_t)p1.x * EMBED_DIM))[lane];
        uint4 a3 = ((const uint4*)(xh + (size_t)p1.z * EMBED_DIM))[lane];
        ACC8(a0, __uint_as_float(p0.y));
        ACC8(a1, __uint_as_float(p0.w));
        ACC8(a2, __uint_as_float(p1.y));
        ACC8(a3, __uint_as_float(p1.w));
    }
    for (; e < e_end; ++e) ACC1(e);
    #undef ACC1
    #undef ACC8

    f32x4 o0 = {A[0], A[1], A[2], A[3]};
    f32x4 o1 = {A[4], A[5], A[6], A[7]};
    f32x4* op = (f32x4*)(out + (size_t)row * EMBED_DIM) + lane * 2;
    __builtin_nontemporal_store(o0, op);
    __builtin_nontemporal_store(o1, op + 1);
}

// ---------------------------------------------------------------------------
// Fallback: atomic COO (f32) if workspace/shape constraints violated.
// ---------------------------------------------------------------------------
__global__ __launch_bounds__(256) void spmv_coo_kernel(
    const void* __restrict__ rows_p, const void* __restrict__ cols_p,
    const float* __restrict__ vals, const float* __restrict__ x,
    float* __restrict__ out, const int* __restrict__ flag_p, int n_edges) {
    const bool i64 = (*flag_p != 0);
    const int lane16 = threadIdx.x & 15;
    long long t      = (long long)blockIdx.x * blockDim.x + threadIdx.x;
    long long stride = (long long)gridDim.x * blockDim.x;
    long long total  = (long long)n_edges * 16;
    for (; t < total; t += stride) {
        int e = (int)(t >> 4);
        int r = load_idx(rows_p, e, i64);
        int c = load_idx(cols_p, e, i64);
        float v = vals[e];
        float4 xv = ((const float4*)(x + (long long)c * EMBED_DIM))[lane16];
        float* o = out + (long long)r * EMBED_DIM + lane16 * 4;
        unsafeAtomicAdd(o + 0, xv.x * v);
        unsafeAtomicAdd(o + 1, xv.y * v);
        unsafeAtomicAdd(o + 2, xv.z * v);
        unsafeAtomicAdd(o + 3, xv.w * v);
    }
}

extern "C" void kernel_launch(void* const* d_in, const int* in_sizes, int n_in,
                              void* d_out, int out_size, void* d_ws, size_t ws_size,
                              hipStream_t stream) {
    const float* x    = (const float*)d_in[0];
    const void*  rows = d_in[1];
    const void*  cols = d_in[2];
    const float* vals = (const float*)d_in[3];
    float* out = (float*)d_out;
    const int E = in_sizes[1];
    const int N = out_size / EMBED_DIM;
    const int NB = (N + RPB - 1) >> RPB_SHIFT;

    // Workspace layout, every section 256B-aligned.
    char* ws = (char*)d_ws;
    size_t off = 0;
    int* flag = (int*)(ws + off);            off += 16;
    int* gcur = (int*)(ws + off);            off += (size_t)NBMAX * 4;
    off = align_up(off, 256);
    ushort* xh = (ushort*)(ws + off);        off += (size_t)N * EMBED_DIM * 2;
    off = align_up(off, 256);
    uint2* srange = (uint2*)(ws + off);      off += (size_t)N * 8;
    off = align_up(off, 256);
    uint2* recs = (uint2*)(ws + off);        off += (size_t)NB * CAP * 8;
    off = align_up(off, 256);
    uint2* recs2 = (uint2*)(ws + off);       off += (size_t)NB * CAP * 8;
    const size_t needed = off;

    if (ws_size < needed || NB > NBMAX || N > (1 << 20) ||
        (size_t)NB * CAP < (size_t)E / 2) {
        detect_zero_kernel<<<1, 1024, 0, stream>>>((const unsigned int*)rows,
                                                   flag, gcur, 0);
        (void)hipMemsetAsync(d_out, 0, (size_t)out_size * sizeof(float), stream);
        spmv_coo_kernel<<<8192, 256, 0, stream>>>(rows, cols, vals, x, out,
                                                  flag, E);
        return;
    }

    const int n8 = N * 8;
    xconv_kernel<<<(n8 + 255) / 256, 256, 0, stream>>>(
        x, xh, n8, (const unsigned int*)rows, flag, gcur, NB);
    const int grid_c = (E + CHUNK - 1) / CHUNK;
    bscatter_kernel<<<grid_c, SCAT_T, SCAT_LDS, stream>>>(
        rows, cols, vals, gcur, recs, flag, E, NB);
    bsort_kernel<<<NB, 512, SORT_LDS, stream>>>(gcur, recs, recs2, srange, N);
    const int grid_g = (N * 8 + 255) / 256;
    gather_kernel<<<grid_g, 256, 0, stream>>>(srange, recs2, xh, out, N);
}

// Round 18
// 132.369 us; speedup vs baseline: 1.2079x; 1.1410x over previous
//
#include <hip/hip_runtime.h>
#include <hip/hip_fp16.h>

#define EMBED_DIM 64
#define NBMAX 1024          // max row buckets (bscatter scan assumes 2*512)
#define RPB 128             // rows per bucket
#define RPB_SHIFT 7
#define CAP 6144            // slots/bucket: mean aligned fill ~5474, +8 sigma
#define CHUNK 8192          // edges per WG = SCAT_T * EPT
#define SCAT_T 512
#define EPT 16              // consecutive edges per thread
#define SENTINEL_KEY 0xFFFFFFFFu   // lr bits >= RPB -> skipped in bsort
// bscatter dynamic LDS: h/gbase/lbase (NBMAX ints each) + tsum[512] + rec[CHUNK]
#define SCAT_LDS (NBMAX * 4 * 3 + 512 * 4 + CHUNK * 8)
// bsort dynamic LDS: lrec[CAP] + cnt/scn/rbase (RPB ints each)
#define SORT_LDS (CAP * 8 + RPB * 4 * 3)

typedef float f32x8 __attribute__((ext_vector_type(8)));
typedef float f32x4 __attribute__((ext_vector_type(4)));

__device__ __forceinline__ int load_idx(const void* p, int e, bool i64) {
    return i64 ? (int)((const long long*)p)[e] : ((const int*)p)[e];
}

static inline size_t align_up(size_t v, size_t a) { return (v + a - 1) & ~(a - 1); }

// ---------------------------------------------------------------------------
// Fallback-path helper: detect index dtype + zero cursors (one WG).
// ---------------------------------------------------------------------------
__global__ __launch_bounds__(1024) void detect_zero_kernel(
    const unsigned int* __restrict__ rows_u32, int* __restrict__ flag,
    int* __restrict__ gcur, int nb) {
    const int tid = threadIdx.x;
    if (tid == 0) {
        int nz = 0;
        for (int i = 1; i < 128; i += 2) nz += (rows_u32[i] != 0u);
        *flag = (nz == 0) ? 1 : 0;
    }
    if (tid < nb) gcur[tid] = 0;
}

// ---------------------------------------------------------------------------
// x (f32) -> xh (fp16, row-major N x 64), detect+cursor-zero fused in block 0
// (flag/gcur consumed only by the later bscatter launch -> stream-ordered).
// ---------------------------------------------------------------------------
__global__ __launch_bounds__(256) void xconv_kernel(
    const float* __restrict__ x, ushort* __restrict__ xh, int n8,
    const unsigned int* __restrict__ rows_u32, int* __restrict__ flag,
    int* __restrict__ gcur, int nb) {
    if (blockIdx.x == 0) {
        if (threadIdx.x == 0) {
            int nz = 0;
            for (int i = 1; i < 128; i += 2) nz += (rows_u32[i] != 0u);
            *flag = (nz == 0) ? 1 : 0;
        }
        for (int j = threadIdx.x; j < nb; j += 256) gcur[j] = 0;
    }
    int i = blockIdx.x * 256 + threadIdx.x;
    if (i >= n8) return;
    float4 a = ((const float4*)x)[i * 2];
    float4 b = ((const float4*)x)[i * 2 + 1];
    ushort h[8];
    h[0] = __half_as_ushort(__float2half_rn(a.x));
    h[1] = __half_as_ushort(__float2half_rn(a.y));
    h[2] = __half_as_ushort(__float2half_rn(a.z));
    h[3] = __half_as_ushort(__float2half_rn(a.w));
    h[4] = __half_as_ushort(__float2half_rn(b.x));
    h[5] = __half_as_ushort(__float2half_rn(b.y));
    h[6] = __half_as_ushort(__float2half_rn(b.z));
    h[7] = __half_as_ushort(__float2half_rn(b.w));
    ((uint4*)xh)[i] = *(const uint4*)h;
}

// ---------------------------------------------------------------------------
// Phase 1 v3: LDS-staged binning with register-batched vector loads.
// Each thread owns 16 CONSECUTIVE edges: rows/cols as uint4 (8 insts i64 /
// 4 insts i32), vals as 4x uint4 -- 20 vector loads replacing r17's 48
// scalar stride-512 loads, all issued up-front for MLP. Copy-out packs 8
// buckets per wave (8 lanes each) -> near-full lane utilization vs r17's
// one-bucket-per-wave (~12/64 lanes).
// ---------------------------------------------------------------------------
__global__ __launch_bounds__(SCAT_T) void bscatter_kernel(
    const void* __restrict__ rows_p, const void* __restrict__ cols_p,
    const float* __restrict__ vals, int* __restrict__ gcur,
    uint2* __restrict__ recs, const int* __restrict__ flag_p,
    int n_edges, int nb) {
    extern __shared__ char smem[];
    int*   h     = (int*)smem;            // NBMAX counts / cursors
    int*   gbase = h + NBMAX;             // NBMAX global run bases
    int*   lbase = gbase + NBMAX;         // NBMAX LDS run bases (compact)
    int*   tsum  = lbase + NBMAX;         // 512 scan workspace
    uint2* rec   = (uint2*)(tsum + 512);  // CHUNK staged records

    const bool i64 = (*flag_p != 0);
    const int tid = threadIdx.x;
    const int e0 = blockIdx.x * CHUNK + tid * EPT;   // this thread's 16 edges
    const bool full = (e0 + EPT) <= n_edges;
    int rr[EPT];

    for (int i = tid; i < NBMAX; i += SCAT_T) h[i] = 0;
    __syncthreads();

    // ---- load rows (vectorized when the whole batch is in range) ----
    if (full) {
        if (i64) {
            const uint4* p = (const uint4*)((const long long*)rows_p + e0);
            #pragma unroll
            for (int q = 0; q < 8; ++q) {
                uint4 u = p[q];
                rr[2 * q]     = (int)u.x;
                rr[2 * q + 1] = (int)u.z;
            }
        } else {
            const uint4* p = (const uint4*)((const int*)rows_p + e0);
            #pragma unroll
            for (int q = 0; q < 4; ++q) {
                uint4 u = p[q];
                rr[4 * q]     = (int)u.x;
                rr[4 * q + 1] = (int)u.y;
                rr[4 * q + 2] = (int)u.z;
                rr[4 * q + 3] = (int)u.w;
            }
        }
    } else {
        #pragma unroll
        for (int k = 0; k < EPT; ++k) {
            int e = e0 + k;
            rr[k] = (e < n_edges) ? load_idx(rows_p, e, i64) : -1;
        }
    }

    #pragma unroll
    for (int k = 0; k < EPT; ++k)
        if (rr[k] >= 0) atomicAdd(&h[rr[k] >> RPB_SHIFT], 1);
    __syncthreads();

    // ---- scan 1024 counts (2/thread) -> LDS bases; reserve aligned runs ----
    const int b0 = 2 * tid, b1 = 2 * tid + 1;
    int cb0 = h[b0], cb1 = h[b1];
    int s = cb0 + cb1;
    tsum[tid] = s;
    __syncthreads();
    for (int d = 1; d < 512; d <<= 1) {
        int u = (tid >= d) ? tsum[tid - d] : 0;
        __syncthreads();
        tsum[tid] += u;
        __syncthreads();
    }
    {
        int run = tsum[tid] - s;
        lbase[b0] = run;
        lbase[b1] = run + cb0;
        int a0 = (cb0 + 7) & ~7, a1 = (cb1 + 7) & ~7;
        gbase[b0] = cb0 ? (b0 * CAP + atomicAdd(&gcur[b0], a0)) : 0;
        gbase[b1] = cb1 ? (b1 * CAP + atomicAdd(&gcur[b1], a1)) : 0;
        h[b0] = 0;
        h[b1] = 0;
    }
    __syncthreads();

    // ---- load cols + vals (vectorized), scatter into LDS ----
    int   cc[EPT];
    float vv[EPT];
    if (full) {
        if (i64) {
            const uint4* p = (const uint4*)((const long long*)cols_p + e0);
            #pragma unroll
            for (int q = 0; q < 8; ++q) {
                uint4 u = p[q];
                cc[2 * q]     = (int)u.x;
                cc[2 * q + 1] = (int)u.z;
            }
        } else {
            const uint4* p = (const uint4*)((const int*)cols_p + e0);
            #pragma unroll
            for (int q = 0; q < 4; ++q) {
                uint4 u = p[q];
                cc[4 * q]     = (int)u.x;
                cc[4 * q + 1] = (int)u.y;
                cc[4 * q + 2] = (int)u.z;
                cc[4 * q + 3] = (int)u.w;
            }
        }
        const float4* pv = (const float4*)(vals + e0);
        #pragma unroll
        for (int q = 0; q < 4; ++q) {
            float4 f = pv[q];
            vv[4 * q]     = f.x;
            vv[4 * q + 1] = f.y;
            vv[4 * q + 2] = f.z;
            vv[4 * q + 3] = f.w;
        }
    } else {
        #pragma unroll
        for (int k = 0; k < EPT; ++k) {
            int e = e0 + k;
            if (rr[k] >= 0) {
                cc[k] = load_idx(cols_p, e, i64);
                vv[k] = vals[e];
            }
        }
    }

    #pragma unroll
    for (int k = 0; k < EPT; ++k) {
        int r = rr[k];
        if (r >= 0) {
            int b = r >> RPB_SHIFT;
            int pos = lbase[b] + atomicAdd(&h[b], 1);
            rec[pos] = make_uint2(
                ((unsigned)(r & (RPB - 1)) << 20) | (unsigned)cc[k],
                __float_as_uint(vv[k]));
        }
    }
    __syncthreads();

    // ---- copy-out: 8 buckets per wave, 8 lanes per bucket ----
    const int wave = tid >> 6, lane = tid & 63;
    const int sub = lane >> 3;          // bucket within the group of 8
    const int slot = lane & 7;          // record slot within a 64B chunk
    for (int bg = wave * 8; bg < nb; bg += (SCAT_T / 64) * 8) {
        int b = bg + sub;
        if (b < nb) {
            int c = h[b];
            if (c > 0) {
                int ca = (c + 7) & ~7;
                int gb = gbase[b], lb = lbase[b];
                int lim = (b + 1) * CAP;
                for (int j = slot; j < ca; j += 8) {
                    uint2 v = (j < c) ? rec[lb + j]
                                      : make_uint2(SENTINEL_KEY, 0u);
                    int pos = gb + j;
                    if (pos < lim) recs[pos] = v;   // overflow guard
                }
            }
        }
    }
}

// ---------------------------------------------------------------------------
// Phase 2: per-bucket counting sort, LDS-staged (r17: one global read of the
// record array instead of two). recs2[pos]={col,val_f32}, srange[row].
// ---------------------------------------------------------------------------
__global__ __launch_bounds__(512) void bsort_kernel(
    const int* __restrict__ gcur, const uint2* __restrict__ recs,
    uint2* __restrict__ recs2, uint2* __restrict__ srange, int N) {
    extern __shared__ char smem[];
    uint2* lrec  = (uint2*)smem;          // CAP staged records
    int*   cnt   = (int*)(lrec + CAP);
    int*   scn   = cnt + RPB;
    int*   rbase = scn + RPB;
    const int b = blockIdx.x;
    const int tid = threadIdx.x;
    const int s = b * CAP;
    int n = gcur[b];
    if (n > CAP) n = CAP;

    if (tid < RPB) cnt[tid] = 0;
    __syncthreads();

    for (int i = tid; i < n; i += 512) {
        uint2 v = recs[s + i];
        lrec[i] = v;
        unsigned lr = v.x >> 20;
        if (lr < RPB) atomicAdd(&cnt[lr], 1);   // skip sentinels
    }
    __syncthreads();

    if (tid < RPB) scn[tid] = cnt[tid];
    __syncthreads();
    for (int d = 1; d < RPB; d <<= 1) {
        int u = (tid < RPB && tid >= d) ? scn[tid - d] : 0;
        __syncthreads();
        if (tid < RPB) scn[tid] += u;
        __syncthreads();
    }
    if (tid < RPB) {
        int excl = scn[tid] - cnt[tid];
        rbase[tid] = excl;
        int row = b * RPB + tid;
        if (row < N) srange[row] = make_uint2(s + excl, s + excl + cnt[tid]);
        cnt[tid] = 0;              // reuse as cursor
    }
    __syncthreads();

    for (int i = tid; i < n; i += 512) {
        uint2 e = lrec[i];
        unsigned lr = e.x >> 20;
        if (lr < RPB) {
            int pos = s + rbase[lr] + atomicAdd(&cnt[lr], 1);
            recs2[pos] = make_uint2(e.x & 0xFFFFFu, e.y);
        }
    }
}

// ---------------------------------------------------------------------------
// Phase 3: row-parallel gather with paired record loads (r17 form).
// ---------------------------------------------------------------------------
__global__ __launch_bounds__(256) void gather_kernel(
    const uint2* __restrict__ srange, const uint2* __restrict__ recs2,
    const ushort* __restrict__ xh, float* __restrict__ out, int N) {
    int t = blockIdx.x * blockDim.x + threadIdx.x;
    int row = t >> 3;
    if (row >= N) return;
    const int lane = t & 7;

    uint2 rg = srange[row];
    int e = (int)rg.x;
    const int e_end = (int)rg.y;
    f32x8 A = {};

    #define ACC8(U, V)                                                     \
        {                                                                  \
            float2 f0 = __half22float2(*(const __half2*)&(U).x);           \
            float2 f1 = __half22float2(*(const __half2*)&(U).y);           \
            float2 f2 = __half22float2(*(const __half2*)&(U).z);           \
            float2 f3 = __half22float2(*(const __half2*)&(U).w);           \
            A[0] += (V) * f0.x; A[1] += (V) * f0.y;                        \
            A[2] += (V) * f1.x; A[3] += (V) * f1.y;                        \
            A[4] += (V) * f2.x; A[5] += (V) * f2.y;                        \
            A[6] += (V) * f3.x; A[7] += (V) * f3.y;                        \
        }
    #define ACC1(E)                                                        \
        {                                                                  \
            uint2 r0 = recs2[E];                                           \
            uint4 a0 = ((const uint4*)(xh + (size_t)r0.x * EMBED_DIM))[lane]; \
            ACC8(a0, __uint_as_float(r0.y));                               \
        }

    if (e < e_end && (e & 1)) { ACC1(e); ++e; }     // align to even index

    for (; e + 4 <= e_end; e += 4) {
        uint4 p0 = *(const uint4*)(recs2 + e);       // records e, e+1
        uint4 p1 = *(const uint4*)(recs2 + e + 2);   // records e+2, e+3
        uint4 a0 = ((const uint4*)(xh + (size_t)p0.x * EMBED_DIM))[lane];
        uint4 a1 = ((const uint4*)(xh + (size_t)p0.z * EMBED_DIM))[lane];
        uint4 a2 = ((const uint4*)(xh + (size_t)p1.x * EMBED_DIM))[lane];
        uint4 a3 = ((const uint4*)(xh + (size_t)p1.z * EMBED_DIM))[lane];
        ACC8(a0, __uint_as_float(p0.y));
        ACC8(a1, __uint_as_float(p0.w));
        ACC8(a2, __uint_as_float(p1.y));
        ACC8(a3, __uint_as_float(p1.w));
    }
    for (; e < e_end; ++e) ACC1(e);
    #undef ACC1
    #undef ACC8

    f32x4 o0 = {A[0], A[1], A[2], A[3]};
    f32x4 o1 = {A[4], A[5], A[6], A[7]};
    f32x4* op = (f32x4*)(out + (size_t)row * EMBED_DIM) + lane * 2;
    __builtin_nontemporal_store(o0, op);
    __builtin_nontemporal_store(o1, op + 1);
}

// ---------------------------------------------------------------------------
// Fallback: atomic COO (f32) if workspace/shape constraints violated.
// ---------------------------------------------------------------------------
__global__ __launch_bounds__(256) void spmv_coo_kernel(
    const void* __restrict__ rows_p, const void* __restrict__ cols_p,
    const float* __restrict__ vals, const float* __restrict__ x,
    float* __restrict__ out, const int* __restrict__ flag_p, int n_edges) {
    const bool i64 = (*flag_p != 0);
    const int lane16 = threadIdx.x & 15;
    long long t      = (long long)blockIdx.x * blockDim.x + threadIdx.x;
    long long stride = (long long)gridDim.x * blockDim.x;
    long long total  = (long long)n_edges * 16;
    for (; t < total; t += stride) {
        int e = (int)(t >> 4);
        int r = load_idx(rows_p, e, i64);
        int c = load_idx(cols_p, e, i64);
        float v = vals[e];
        float4 xv = ((const float4*)(x + (long long)c * EMBED_DIM))[lane16];
        float* o = out + (long long)r * EMBED_DIM + lane16 * 4;
        unsafeAtomicAdd(o + 0, xv.x * v);
        unsafeAtomicAdd(o + 1, xv.y * v);
        unsafeAtomicAdd(o + 2, xv.z * v);
        unsafeAtomicAdd(o + 3, xv.w * v);
    }
}

extern "C" void kernel_launch(void* const* d_in, const int* in_sizes, int n_in,
                              void* d_out, int out_size, void* d_ws, size_t ws_size,
                              hipStream_t stream) {
    const float* x    = (const float*)d_in[0];
    const void*  rows = d_in[1];
    const void*  cols = d_in[2];
    const float* vals = (const float*)d_in[3];
    float* out = (float*)d_out;
    const int E = in_sizes[1];
    const int N = out_size / EMBED_DIM;
    const int NB = (N + RPB - 1) >> RPB_SHIFT;

    // Workspace layout, every section 256B-aligned.
    char* ws = (char*)d_ws;
    size_t off = 0;
    int* flag = (int*)(ws + off);            off += 16;
    int* gcur = (int*)(ws + off);            off += (size_t)NBMAX * 4;
    off = align_up(off, 256);
    ushort* xh = (ushort*)(ws + off);        off += (size_t)N * EMBED_DIM * 2;
    off = align_up(off, 256);
    uint2* srange = (uint2*)(ws + off);      off += (size_t)N * 8;
    off = align_up(off, 256);
    uint2* recs = (uint2*)(ws + off);        off += (size_t)NB * CAP * 8;
    off = align_up(off, 256);
    uint2* recs2 = (uint2*)(ws + off);       off += (size_t)NB * CAP * 8;
    const size_t needed = off;

    if (ws_size < needed || NB > NBMAX || N > (1 << 20) ||
        (size_t)NB * CAP < (size_t)E / 2) {
        detect_zero_kernel<<<1, 1024, 0, stream>>>((const unsigned int*)rows,
                                                   flag, gcur, 0);
        (void)hipMemsetAsync(d_out, 0, (size_t)out_size * sizeof(float), stream);
        spmv_coo_kernel<<<8192, 256, 0, stream>>>(rows, cols, vals, x, out,
                                                  flag, E);
        return;
    }

    const int n8 = N * 8;
    xconv_kernel<<<(n8 + 255) / 256, 256, 0, stream>>>(
        x, xh, n8, (const unsigned int*)rows, flag, gcur, NB);
    const int grid_c = (E + CHUNK - 1) / CHUNK;
    bscatter_kernel<<<grid_c, SCAT_T, SCAT_LDS, stream>>>(
        rows, cols, vals, gcur, recs, flag, E, NB);
    bsort_kernel<<<NB, 512, SORT_LDS, stream>>>(gcur, recs, recs2, srange, N);
    const int grid_g = (N * 8 + 255) / 256;
    gather_kernel<<<grid_g, 256, 0, stream>>>(srange, recs2, xh, out, N);
}